// Round 6
// baseline (165.324 us; speedup 1.0000x reference)
//
#include <hip/hip_runtime.h>
#include <math.h>

// out [1, 128, N] f32:
//   rows   0.. 63 : pdf^T               (pdf [N,64] row-major)
//   rows  64.. 95 : te[c] broadcast     (timestep embedding, single vector)
//   rows  96..127 : mask[p] ? me1[c] : me0[c]
//
// ws layout: te[0..31], me0[32..63], me1[64..95]
//
// R5 = R4 with the compile fix (ext_vector int4 for nt mask load):
//   128-pt tiles x 512 threads, channel-major LDS [64][128] with XOR swizzle
//   (32 KB -> 4 blocks/CU -> 32 waves/CU full occupancy),
//   float4 nontemporal stores (1KB/wave-instr), nt loads, m204 XCD swizzle.

#define HALF 32
#define TP 128   // points per tile

typedef float v4f __attribute__((ext_vector_type(4)));
typedef int   v4i __attribute__((ext_vector_type(4)));

// channel-major swizzled index: c in [0,64), p in [0,128)
__device__ __forceinline__ int ldsIdx(int c, int p) {
    return (c << 7) + (p ^ (((c >> 2) & 7) << 2));
}

__global__ void embed_small_kernel(const float* __restrict__ t,
                                   const float* __restrict__ ef_w1, const float* __restrict__ ef_b1,
                                   const float* __restrict__ ef_w2, const float* __restrict__ ef_b2,
                                   const float* __restrict__ em_w1, const float* __restrict__ em_b1,
                                   const float* __restrict__ em_w2, const float* __restrict__ em_b2,
                                   float* __restrict__ ws) {
    __shared__ float h[3][64];
    const int tid = threadIdx.x;
    const float log_scale = 0.2970934777f;  // ln(10000)/31

    if (tid < 192) {
        const int v = tid >> 6;      // 0: sin-emb(t)->ef, 1: sin-emb(0)->em, 2: sin-emb(1)->em
        const int j = tid & 63;
        const float val = (v == 0) ? t[0] : (float)(v - 1);
        const float* w1 = (v == 0) ? ef_w1 : em_w1;
        const float* b1 = (v == 0) ? ef_b1 : em_b1;
        float acc = b1[j];
        for (int k = 0; k < HALF; ++k) {
            float f = expf(-(float)k * log_scale);
            float ang = val * f;
            float s, c;
            sincosf(ang, &s, &c);
            acc += s * w1[j * 64 + k] + c * w1[j * 64 + HALF + k];
        }
        h[v][j] = (acc > 0.0f) ? acc : 0.1f * acc;  // LeakyReLU(0.1)
    }
    __syncthreads();
    if (tid < 96) {
        const int v = tid >> 5;
        const int c = tid & 31;
        const float* w2 = (v == 0) ? ef_w2 : em_w2;
        const float* b2 = (v == 0) ? ef_b2 : em_b2;
        float acc = b2[c];
        for (int j = 0; j < 64; ++j) acc += h[v][j] * w2[c * 64 + j];
        ws[v * 32 + c] = acc;
    }
}

__global__ __launch_bounds__(512) void pvcnn_cond_kernel(
        const float* __restrict__ pdf,
        const int* __restrict__ mask,
        const float* __restrict__ ws,
        float* __restrict__ out,
        int N) {
    __shared__ float tile[64 * TP];   // 32 KB, channel-major swizzled
    __shared__ float emb[96];

    const int tid = threadIdx.x;

    // ---- bijective XCD-contiguous swizzle (m204) ----
    const int nwg = gridDim.x;
    const int q   = nwg >> 3;
    const int r8  = nwg & 7;
    const int xcd = blockIdx.x & 7;
    const int j8  = blockIdx.x >> 3;
    const int bid = (xcd < r8 ? xcd * (q + 1) : r8 * (q + 1) + (xcd - r8) * q) + j8;

    const long long p0 = (long long)bid * TP;
    const bool full = (p0 + TP <= (long long)N);

    if (tid < 96) emb[tid] = ws[tid];

    // ---- phase 1: pdf tile -> LDS (channel-major, swizzled; nt loads) ----
    if (full) {
        const v4f* src = (const v4f*)(pdf + p0 * 64);
        #pragma unroll
        for (int it = 0; it < 4; ++it) {
            const int f = tid + it * 512;     // 0..2047
            const int p = f >> 4;             // point 0..127
            const int k = f & 15;             // c0 = 4k
            const v4f v = __builtin_nontemporal_load(src + f);
            const int b = ldsIdx(4 * k, p);   // rows 4k..4k+3 share the swizzle
            tile[b + 0 * TP] = v.x;
            tile[b + 1 * TP] = v.y;
            tile[b + 2 * TP] = v.z;
            tile[b + 3 * TP] = v.w;
        }
    } else {
        #pragma unroll
        for (int it = 0; it < 4; ++it) {
            const int f = tid + it * 512;
            const int p = f >> 4;
            const int k = f & 15;
            v4f v = {0.f, 0.f, 0.f, 0.f};
            if (p0 + p < (long long)N)
                v = __builtin_nontemporal_load((const v4f*)(pdf + (p0 + p) * 64) + k);
            const int b = ldsIdx(4 * k, p);
            tile[b + 0 * TP] = v.x;
            tile[b + 1 * TP] = v.y;
            tile[b + 2 * TP] = v.z;
            tile[b + 3 * TP] = v.w;
        }
    }

    // this thread's fixed 4 columns for phase 2: cols p0 + 4*c4 .. +3
    const int c4 = tid & 31;          // float4 group within row
    const int rb = tid >> 5;          // row base 0..15
    const long long col = p0 + 4 * c4;

    v4i m4 = {0, 0, 0, 0};
    if (full) {
        m4 = __builtin_nontemporal_load((const v4i*)mask + (p0 >> 2) + c4);
    } else {
        if (col + 0 < N) m4.x = mask[col + 0];
        if (col + 1 < N) m4.y = mask[col + 1];
        if (col + 2 < N) m4.z = mask[col + 2];
        if (col + 3 < N) m4.w = mask[col + 3];
    }

    __syncthreads();

    // ---- phase 2: 128 rows; r = rb + 16*it; float4 nt stores ----
    if (full) {
        #pragma unroll
        for (int it = 0; it < 8; ++it) {
            const int r = rb + 16 * it;
            v4f v;
            if (it < 4) {                 // rows 0..63: transpose
                v = *(const v4f*)&tile[ldsIdx(r, 4 * c4)];
            } else if (it < 6) {          // rows 64..95: te broadcast
                const float e = emb[r - 64];
                v = (v4f){e, e, e, e};
            } else {                      // rows 96..127: mask embedding
                const int c = r - 96;
                const float e0 = emb[32 + c];
                const float e1 = emb[64 + c];
                v = (v4f){m4.x ? e1 : e0, m4.y ? e1 : e0,
                          m4.z ? e1 : e0, m4.w ? e1 : e0};
            }
            __builtin_nontemporal_store(v, (v4f*)(out + (long long)r * N + col));
        }
    } else {
        for (int it = 0; it < 8; ++it) {
            const int r = rb + 16 * it;
            float vals[4];
            if (it < 4) {
                #pragma unroll
                for (int d = 0; d < 4; ++d) vals[d] = tile[ldsIdx(r, 4 * c4 + d)];
            } else if (it < 6) {
                const float e = emb[r - 64];
                vals[0] = vals[1] = vals[2] = vals[3] = e;
            } else {
                const int c = r - 96;
                const float e0 = emb[32 + c];
                const float e1 = emb[64 + c];
                vals[0] = m4.x ? e1 : e0;
                vals[1] = m4.y ? e1 : e0;
                vals[2] = m4.z ? e1 : e0;
                vals[3] = m4.w ? e1 : e0;
            }
            #pragma unroll
            for (int d = 0; d < 4; ++d)
                if (col + d < (long long)N)
                    out[(long long)r * N + col + d] = vals[d];
        }
    }
}

extern "C" void kernel_launch(void* const* d_in, const int* in_sizes, int n_in,
                              void* d_out, int out_size, void* d_ws, size_t ws_size,
                              hipStream_t stream) {
    // 0: inputs [1,6,N]; 1: t [1]; 2: mask [N] i32; 3: pdf [N,64];
    // 4..7: ef_w1,ef_b1,ef_w2,ef_b2; 8..11: em_w1,em_b1,em_w2,em_b2
    const float* t     = (const float*)d_in[1];
    const int*   mask  = (const int*)d_in[2];
    const float* pdf   = (const float*)d_in[3];
    const float* ef_w1 = (const float*)d_in[4];
    const float* ef_b1 = (const float*)d_in[5];
    const float* ef_w2 = (const float*)d_in[6];
    const float* ef_b2 = (const float*)d_in[7];
    const float* em_w1 = (const float*)d_in[8];
    const float* em_b1 = (const float*)d_in[9];
    const float* em_w2 = (const float*)d_in[10];
    const float* em_b2 = (const float*)d_in[11];

    float* out = (float*)d_out;
    float* ws  = (float*)d_ws;
    const int N = in_sizes[2];

    embed_small_kernel<<<1, 192, 0, stream>>>(t, ef_w1, ef_b1, ef_w2, ef_b2,
                                              em_w1, em_b1, em_w2, em_b2, ws);

    const int nblocks = (N + TP - 1) / TP;
    pvcnn_cond_kernel<<<nblocks, 512, 0, stream>>>(pdf, mask, ws, out, N);
}

// Round 7
// 136.508 us; speedup vs baseline: 1.2111x; 1.2111x over previous
//
#include <hip/hip_runtime.h>
#include <math.h>

// out [1, 128, N] f32:
//   rows   0.. 63 : pdf^T               (pdf [N,64] row-major)
//   rows  64.. 95 : te[c] broadcast     (timestep embedding, single vector)
//   rows  96..127 : mask[p] ? me1[c] : me0[c]
//
// ws layout: te[0..31], me0[32..63], me1[64..95]
//
// R6 = R3 (best so far: 64-pt tiles, 256 thr, [64][65] LDS, scalar NT stores,
//          m204 XCD swizzle) with ONE change:
//   loads of pdf/mask are TEMPORAL (regular) so pdf (256 MB == L3 size) can
//   stay resident in Infinity Cache across graph replays, while NT stores
//   stream the 512 MB output past the caches without evicting it.

#define HALF 32

typedef float v4f __attribute__((ext_vector_type(4)));

__global__ void embed_small_kernel(const float* __restrict__ t,
                                   const float* __restrict__ ef_w1, const float* __restrict__ ef_b1,
                                   const float* __restrict__ ef_w2, const float* __restrict__ ef_b2,
                                   const float* __restrict__ em_w1, const float* __restrict__ em_b1,
                                   const float* __restrict__ em_w2, const float* __restrict__ em_b2,
                                   float* __restrict__ ws) {
    __shared__ float h[3][64];
    const int tid = threadIdx.x;
    const float log_scale = 0.2970934777f;  // ln(10000)/31

    if (tid < 192) {
        const int v = tid >> 6;      // 0: sin-emb(t)->ef, 1: sin-emb(0)->em, 2: sin-emb(1)->em
        const int j = tid & 63;
        const float val = (v == 0) ? t[0] : (float)(v - 1);
        const float* w1 = (v == 0) ? ef_w1 : em_w1;
        const float* b1 = (v == 0) ? ef_b1 : em_b1;
        float acc = b1[j];
        for (int k = 0; k < HALF; ++k) {
            float f = expf(-(float)k * log_scale);
            float ang = val * f;
            float s, c;
            sincosf(ang, &s, &c);
            acc += s * w1[j * 64 + k] + c * w1[j * 64 + HALF + k];
        }
        h[v][j] = (acc > 0.0f) ? acc : 0.1f * acc;  // LeakyReLU(0.1)
    }
    __syncthreads();
    if (tid < 96) {
        const int v = tid >> 5;
        const int c = tid & 31;
        const float* w2 = (v == 0) ? ef_w2 : em_w2;
        const float* b2 = (v == 0) ? ef_b2 : em_b2;
        float acc = b2[c];
        for (int j = 0; j < 64; ++j) acc += h[v][j] * w2[c * 64 + j];
        ws[v * 32 + c] = acc;
    }
}

__global__ __launch_bounds__(256) void pvcnn_cond_kernel(
        const float* __restrict__ pdf,
        const int* __restrict__ mask,
        const float* __restrict__ ws,
        float* __restrict__ out,
        int N) {
    __shared__ float tile[64][65];
    __shared__ float emb[96];

    const int tid = threadIdx.x;

    // ---- bijective XCD-contiguous swizzle (m204) ----
    const int nwg  = gridDim.x;
    const int q    = nwg >> 3;
    const int r    = nwg & 7;
    const int xcd  = blockIdx.x & 7;
    const int j    = blockIdx.x >> 3;
    const int bid  = (xcd < r ? xcd * (q + 1) : r * (q + 1) + (xcd - r) * q) + j;

    const long long p0 = (long long)bid * 64;
    const bool full = (p0 + 64 <= (long long)N);

    if (tid < 96) emb[tid] = ws[tid];

    // ---- phase 1: pdf tile -> LDS (TEMPORAL loads; let L3 keep pdf) ----
    if (full) {
        const v4f* pdf4 = (const v4f*)(pdf + p0 * 64);
        #pragma unroll
        for (int it = 0; it < 4; ++it) {
            int f = tid + it * 256;          // 0..1023
            int p = f >> 4;
            int qq = f & 15;
            v4f v = pdf4[p * 16 + qq];
            tile[p][4 * qq + 0] = v.x;
            tile[p][4 * qq + 1] = v.y;
            tile[p][4 * qq + 2] = v.z;
            tile[p][4 * qq + 3] = v.w;
        }
    } else {
        #pragma unroll
        for (int it = 0; it < 4; ++it) {
            int f = tid + it * 256;
            int p = f >> 4;
            int qq = f & 15;
            v4f v = {0.f, 0.f, 0.f, 0.f};
            if (p0 + p < (long long)N) {
                const v4f* pdf4 = (const v4f*)(pdf + (p0 + p) * 64);
                v = pdf4[qq];
            }
            tile[p][4 * qq + 0] = v.x;
            tile[p][4 * qq + 1] = v.y;
            tile[p][4 * qq + 2] = v.z;
            tile[p][4 * qq + 3] = v.w;
        }
    }

    const int p  = tid & 63;       // point within tile
    const int wv = tid >> 6;       // wave id 0..3 -> channel sub-offset
    const bool pok = (p0 + p < (long long)N);
    int mval = 0;
    if (pok) mval = mask[p0 + p];

    __syncthreads();

    // ---- phase 2: 128 rows, r = cb + wv; NT scalar stores (stream past L3) ----
    if (pok) {
        const long long col = p0 + p;
        // pdf^T rows 0..63
        #pragma unroll
        for (int cb = 0; cb < 64; cb += 4) {
            int c = cb + wv;
            __builtin_nontemporal_store(tile[p][c], out + (long long)c * N + col);
        }
        // te broadcast rows 64..95
        #pragma unroll
        for (int cb = 0; cb < 32; cb += 4) {
            int c = cb + wv;
            __builtin_nontemporal_store(emb[c], out + (long long)(64 + c) * N + col);
        }
        // mask-embedding rows 96..127
        #pragma unroll
        for (int cb = 0; cb < 32; cb += 4) {
            int c = cb + wv;
            __builtin_nontemporal_store(mval ? emb[64 + c] : emb[32 + c],
                                        out + (long long)(96 + c) * N + col);
        }
    }
}

extern "C" void kernel_launch(void* const* d_in, const int* in_sizes, int n_in,
                              void* d_out, int out_size, void* d_ws, size_t ws_size,
                              hipStream_t stream) {
    // 0: inputs [1,6,N]; 1: t [1]; 2: mask [N] i32; 3: pdf [N,64];
    // 4..7: ef_w1,ef_b1,ef_w2,ef_b2; 8..11: em_w1,em_b1,em_w2,em_b2
    const float* t     = (const float*)d_in[1];
    const int*   mask  = (const int*)d_in[2];
    const float* pdf   = (const float*)d_in[3];
    const float* ef_w1 = (const float*)d_in[4];
    const float* ef_b1 = (const float*)d_in[5];
    const float* ef_w2 = (const float*)d_in[6];
    const float* ef_b2 = (const float*)d_in[7];
    const float* em_w1 = (const float*)d_in[8];
    const float* em_b1 = (const float*)d_in[9];
    const float* em_w2 = (const float*)d_in[10];
    const float* em_b2 = (const float*)d_in[11];

    float* out = (float*)d_out;
    float* ws  = (float*)d_ws;
    const int N = in_sizes[2];

    embed_small_kernel<<<1, 192, 0, stream>>>(t, ef_w1, ef_b1, ef_w2, ef_b2,
                                              em_w1, em_b1, em_w2, em_b2, ws);

    const int nblocks = (N + 63) / 64;
    pvcnn_cond_kernel<<<nblocks, 256, 0, stream>>>(pdf, mask, ws, out, N);
}